// Round 9
// baseline (19.450 us; speedup 1.0000x reference)
//
#include <hip/hip_runtime.h>
#include <hip/hip_fp16.h>

#define TILE 16
#define PPT 64

#if __has_builtin(__builtin_amdgcn_exp2f)
#define EXP2F(x) __builtin_amdgcn_exp2f(x)
#else
#define EXP2F(x) exp2f(x)
#endif

// Robustly read a small positive integer scalar that may have been stored
// as int32 or float32 bits.
__device__ __forceinline__ int read_dim(const int* p) {
    int v = *p;
    if (v >= TILE && v <= 65536 && (v % TILE) == 0) return v;
    float f = __int_as_float(v);
    return (int)f;
}

struct Acc {
    float T, Tg, r, g, b, d;
    int cnt, last;
};

// One serial compositing step from precomputed (e, alpha).
// Slim bookkeeping, exactly equivalent to the reference semantics:
//   alpha_g = vis ? alpha : 0  ->  om == 1.0f bit-exact for invisible points
//   Tg invariant: Tg in {0} U [1e-4, 1];  T == Tg until saturation trigger.
//   contrib <=> w > 0;  telescoping: sum(w) == 1 - T_final.
__device__ __forceinline__ void step(
    float e, float alpha, const float4& C, int jp1, Acc& a)
{
    const bool  vis   = e >= -7.9943533f;            // log2(1/255)
    const float ag    = vis ? alpha : 0.0f;
    const float om    = fmaxf(1.0f - ag, 0.01f);     // 1 - min(alpha_g,0.99)
    const float Tone  = a.Tg * om;
    const bool  ntrig = Tone >= 1e-4f;
    const float diff  = a.Tg - Tone;                 // == alpha_c * Ti
    const float w     = ntrig ? diff : 0.0f;
    const bool  contrib = w > 0.0f;
    a.r = fmaf(w, C.x, a.r);  a.g = fmaf(w, C.y, a.g);
    a.b = fmaf(w, C.z, a.b);  a.d = fmaf(w, C.w, a.d);
    a.cnt += contrib;
    a.last = contrib ? jp1 : a.last;
    a.T  = ntrig ? Tone : a.T;    // !vis: Tone==Tg==T (om==1.0) -> no change
    a.Tg = ntrig ? Tone : 0.0f;   // trigger (vis & Tone<1e-4) -> sentinel 0
}

// One block = one tile = 128 threads (2 waves); thread p composites pixels
// (pv0, pu) and (pv0+8, pu) — same column, sharing dx/q/base per point.
// Phase-split schedule (independent e/exp math batched into registers,
// then short serial T-chains). LDS repacked to TWO b128 reads per point.
__global__ __launch_bounds__(128, 2) void gsplat_raster_kernel(
    const float* __restrict__ point_uv,          // (N,2)
    const float* __restrict__ point_conic,       // (N,3)
    const float* __restrict__ point_alpha,       // (N,)
    const float* __restrict__ point_color,       // (N,3)
    const float* __restrict__ point_depth,       // (N,)
    const int*   __restrict__ tile_point_indices,// (NT,PPT)
    const int*   __restrict__ cam_h_p,
    const int*   __restrict__ cam_w_p,
    float* __restrict__ out)
{
    const int t = blockIdx.x;
    const int p = threadIdx.x;   // 0..127

    const int W  = read_dim(cam_w_p);
    const int H  = read_dim(cam_h_p);
    const int TU = W / TILE;
    const int n_pix = H * W;

    // sAB = {u, v, -0.5*log2e*a, -0.5*log2e*c}
    // sCD = {-log2e*b, log2(alpha), half2(r,g), half2(b,depth)}
    __shared__ float4 sAB[PPT];
    __shared__ float4 sCD[PPT];

    const float L2E = 1.4426950408889634f;
    if (p < PPT) {                       // wave 0: geometry side
        const int gi = tile_point_indices[t * PPT + p];
        const float2 uv = ((const float2*)point_uv)[gi];
        sAB[p] = make_float4(uv.x, uv.y,
                             -0.5f * L2E * point_conic[gi * 3 + 0],
                             -0.5f * L2E * point_conic[gi * 3 + 2]);
    } else {                             // wave 1: attributes side
        const int q  = p - PPT;
        const int gi = tile_point_indices[t * PPT + q];
        const __half2 rg = __floats2half2_rn(point_color[gi * 3 + 0],
                                             point_color[gi * 3 + 1]);
        const __half2 bd = __floats2half2_rn(point_color[gi * 3 + 2],
                                             point_depth[gi]);
        sCD[q] = make_float4(-L2E * point_conic[gi * 3 + 1],
                             __log2f(point_alpha[gi]),
                             __builtin_bit_cast(float, rg),
                             __builtin_bit_cast(float, bd));
    }
    __syncthreads();

    const int tu  = t % TU;
    const int tv  = t / TU;
    const int pu  = p % TILE;
    const int pv0 = p / TILE;      // rows 0..7 (second pixel = +8)
    const float pix_u  = (float)(tu * TILE + pu) + 0.5f;
    const float pix_v0 = (float)(tv * TILE + pv0) + 0.5f;

    Acc a0 = {1.0f, 1.0f, 0.f, 0.f, 0.f, 0.f, 0, 0};
    Acc a1 = {1.0f, 1.0f, 0.f, 0.f, 0.f, 0.f, 0, 0};

    #pragma unroll 1
    for (int g = 0; g < PPT / 8; ++g) {          // groups of 8 points
        const int gb = g * 8;

        // ---- phase 1: independent math into register arrays ----
        float  e0[8], e1[8], al0[8], al1[8];
        float4 C[8];
        #pragma unroll
        for (int k = 0; k < 8; ++k) {
            const int j = gb + k;
            const float4 A = sAB[j];   // wave-uniform broadcast
            const float4 D = sCD[j];
            const float dx   = pix_u - A.x;
            const float q    = D.x * dx;                 // pb*dx
            const float base = fmaf(A.z * dx, dx, D.y);  // pa*dx^2+lal
            const float dy0  = pix_v0 - A.y;
            const float dy1  = dy0 + 8.0f;
            e0[k] = fmaf(fmaf(A.w, dy0, q), dy0, base);
            e1[k] = fmaf(fmaf(A.w, dy1, q), dy1, base);
            al0[k] = EXP2F(e0[k]);
            al1[k] = EXP2F(e1[k]);
            const __half2 rg = __builtin_bit_cast(__half2, D.z);
            const __half2 bd = __builtin_bit_cast(__half2, D.w);
            C[k] = make_float4(__low2float(rg), __high2float(rg),
                               __low2float(bd), __high2float(bd));
        }

        // ---- phase 2: serial chains from registers ----
        #pragma unroll
        for (int k = 0; k < 8; ++k) {
            const int jp1 = gb + k + 1;
            step(e0[k], al0[k], C[k], jp1, a0);
            step(e1[k], al1[k], C[k], jp1, a1);
        }

        // exact skip: Tg==0 makes all remaining steps no-ops
        if (__all((a0.Tg == 0.0f) && (a1.Tg == 0.0f))) break;
    }

    // ---- write outputs (image layout) ----
    const int c    = tu * TILE + pu;
    const int row0 = tv * TILE + pv0;
    const int pix0 = row0 * W + c;
    const int pix1 = pix0 + 8 * W;

    const float norm0 = 1.0f - a0.T;   // == sum(w) by telescoping
    const float norm1 = 1.0f - a1.T;

    out[pix0 * 3 + 0] = a0.r;
    out[pix0 * 3 + 1] = a0.g;
    out[pix0 * 3 + 2] = a0.b;
    out[n_pix * 3 + pix0] = a0.d / fmaxf(norm0, 1e-6f);
    out[n_pix * 4 + pix0] = norm0;
    out[n_pix * 5 + pix0] = (float)(t * PPT + a0.last);
    out[n_pix * 6 + pix0] = (float)a0.cnt;

    out[pix1 * 3 + 0] = a1.r;
    out[pix1 * 3 + 1] = a1.g;
    out[pix1 * 3 + 2] = a1.b;
    out[n_pix * 3 + pix1] = a1.d / fmaxf(norm1, 1e-6f);
    out[n_pix * 4 + pix1] = norm1;
    out[n_pix * 5 + pix1] = (float)(t * PPT + a1.last);
    out[n_pix * 6 + pix1] = (float)a1.cnt;
}

extern "C" void kernel_launch(void* const* d_in, const int* in_sizes, int n_in,
                              void* d_out, int out_size, void* d_ws, size_t ws_size,
                              hipStream_t stream) {
    const float* point_uv    = (const float*)d_in[0];
    const float* point_conic = (const float*)d_in[1];
    const float* point_alpha = (const float*)d_in[2];
    const float* point_color = (const float*)d_in[3];
    const float* point_depth = (const float*)d_in[4];
    const int*   tpi         = (const int*)d_in[5];
    const int*   cam_h       = (const int*)d_in[6];
    const int*   cam_w       = (const int*)d_in[7];

    const int NT = in_sizes[5] / PPT;  // number of tiles

    gsplat_raster_kernel<<<NT, 128, 0, stream>>>(
        point_uv, point_conic, point_alpha, point_color, point_depth,
        tpi, cam_h, cam_w, (float*)d_out);
}

// Round 10
// 18.350 us; speedup vs baseline: 1.0599x; 1.0599x over previous
//
#include <hip/hip_runtime.h>

#define TILE 16
#define PPT 64

#if __has_builtin(__builtin_amdgcn_exp2f)
#define EXP2F(x) __builtin_amdgcn_exp2f(x)
#else
#define EXP2F(x) exp2f(x)
#endif

// Robustly read a small positive integer scalar that may have been stored
// as int32 or float32 bits.
__device__ __forceinline__ int read_dim(const int* p) {
    int v = *p;
    if (v >= TILE && v <= 65536 && (v % TILE) == 0) return v;
    float f = __int_as_float(v);
    return (int)f;
}

// Prefix products P[k] = om[0]*...*om[k] via a multiply tree (depth ~4
// instead of a serial 8-chain). om[k] == 1.0f exactly for invisible points,
// so their prefix step is bit-exact identity.
__device__ __forceinline__ void prefix8(const float om[8], float P[8]) {
    const float m01 = om[0] * om[1], m23 = om[2] * om[3];
    const float m45 = om[4] * om[5], m67 = om[6] * om[7];
    const float m03 = m01 * m23;
    const float t6  = m45 * om[6];
    const float m47 = m45 * m67;
    P[0] = om[0];        P[1] = m01;
    P[2] = m01 * om[2];  P[3] = m03;
    P[4] = m03 * om[4];  P[5] = m03 * m45;
    P[6] = m03 * t6;     P[7] = m03 * m47;
}

// Composite one group of 8 points for one pixel from prefix products.
// Within a group Tone_k = Tg_in * P[k] is monotone non-increasing, so:
//  - saturation trigger == first crossing below 1e-4 (crossing step is
//    always a visible step, since only om<1 decreases the product);
//  - w_k = Tone_{k-1} - Tone_k equals alpha_c*Ti for contributing points,
//    and is EXACTLY 0 for invisible points (om==1.0 -> identical prefix);
//  - contrib <=> w > 0 (visible ntrig steps shrink Tone by >=0.39%).
// T freezes at the last contribution; Tg_out = 0 once triggered (sentinel).
__device__ __forceinline__ void group8(
    const float P[8], const float4 C[8], int gb,
    float& Tg, float& T, float& ar, float& ag, float& ab, float& ad,
    int& cnt, int& last)
{
    float Tprev = Tg;
    #pragma unroll
    for (int k = 0; k < 8; ++k) {
        const float Tone  = Tg * P[k];          // independent of each other
        const bool  ntrig = Tone >= 1e-4f;
        const float w     = ntrig ? (Tprev - Tone) : 0.0f;
        ar = fmaf(w, C[k].x, ar);  ag = fmaf(w, C[k].y, ag);
        ab = fmaf(w, C[k].z, ab);  ad = fmaf(w, C[k].w, ad);
        const bool contrib = w > 0.0f;
        cnt += contrib;
        last = contrib ? gb + k + 1 : last;
        T = contrib ? Tone : T;
        Tprev = Tone;                           // register rename only
    }
    Tg = (Tprev >= 1e-4f) ? Tprev : 0.0f;
}

// One block = one tile = 128 threads (2 waves); thread p composites pixels
// (pv0, pu) and (pv0+8, pu) — same column, sharing dx/q/base per point.
// Phase 1 batches all independent math (e, exp2, om) into registers;
// phase 2 uses prefix products so the T-"chain" has depth ~6 per 8 points.
__global__ __launch_bounds__(128, 2) void gsplat_raster_kernel(
    const float* __restrict__ point_uv,          // (N,2)
    const float* __restrict__ point_conic,       // (N,3)
    const float* __restrict__ point_alpha,       // (N,)
    const float* __restrict__ point_color,       // (N,3)
    const float* __restrict__ point_depth,       // (N,)
    const int*   __restrict__ tile_point_indices,// (NT,PPT)
    const int*   __restrict__ cam_h_p,
    const int*   __restrict__ cam_w_p,
    float* __restrict__ out)
{
    const int t = blockIdx.x;
    const int p = threadIdx.x;   // 0..127

    const int W  = read_dim(cam_w_p);
    const int H  = read_dim(cam_h_p);
    const int TU = W / TILE;
    const int n_pix = H * W;

    // sA = {u, v, -0.5*log2e*a, -0.5*log2e*c}; sB = {-log2e*b, log2(alpha)};
    // sC = {r, g, b, depth}  (all f32 — R9's f16 pack regressed)
    __shared__ float4 sA[PPT];
    __shared__ float2 sB[PPT];
    __shared__ float4 sC[PPT];

    const float L2E = 1.4426950408889634f;
    if (p < PPT) {                       // wave 0: geometry side
        const int gi = tile_point_indices[t * PPT + p];
        const float2 uv = ((const float2*)point_uv)[gi];
        sA[p] = make_float4(uv.x, uv.y,
                            -0.5f * L2E * point_conic[gi * 3 + 0],
                            -0.5f * L2E * point_conic[gi * 3 + 2]);
        sB[p] = make_float2(-L2E * point_conic[gi * 3 + 1],
                            __log2f(point_alpha[gi]));
    } else {                             // wave 1: color/depth side
        const int q  = p - PPT;
        const int gi = tile_point_indices[t * PPT + q];
        sC[q] = make_float4(point_color[gi * 3 + 0],
                            point_color[gi * 3 + 1],
                            point_color[gi * 3 + 2],
                            point_depth[gi]);
    }
    __syncthreads();

    const int tu  = t % TU;
    const int tv  = t / TU;
    const int pu  = p % TILE;
    const int pv0 = p / TILE;      // rows 0..7 (second pixel = +8)
    const float pix_u  = (float)(tu * TILE + pu) + 0.5f;
    const float pix_v0 = (float)(tv * TILE + pv0) + 0.5f;

    float T0 = 1.0f, Tg0 = 1.0f, r0 = 0.f, g0 = 0.f, b0 = 0.f, d0 = 0.f;
    float T1 = 1.0f, Tg1 = 1.0f, r1 = 0.f, g1 = 0.f, b1 = 0.f, d1 = 0.f;
    int cnt0 = 0, cnt1 = 0, last0 = 0, last1 = 0;

    #pragma unroll 1
    for (int sg = 0; sg < PPT / 16; ++sg) {      // supergroups of 16 points
        #pragma unroll
        for (int h = 0; h < 2; ++h) {            // 2 groups of 8, same BB
            const int gb = sg * 16 + h * 8;

            // ---- phase 1: independent math into register arrays ----
            float  om0[8], om1[8];
            float4 C[8];
            #pragma unroll
            for (int k = 0; k < 8; ++k) {
                const int j = gb + k;
                const float4 A = sA[j];   // wave-uniform broadcast
                const float2 B = sB[j];
                C[k] = sC[j];
                const float dx   = pix_u - A.x;
                const float q    = B.x * dx;                 // pb*dx
                const float base = fmaf(A.z * dx, dx, B.y);  // pa*dx^2+lal
                const float dy0  = pix_v0 - A.y;
                const float dy1  = dy0 + 8.0f;
                const float al0  = EXP2F(fmaf(fmaf(A.w, dy0, q), dy0, base));
                const float al1  = EXP2F(fmaf(fmaf(A.w, dy1, q), dy1, base));
                // om = 1 - alpha_c, gated EXACTLY to 1.0 for invisible
                om0[k] = (al0 >= 1.0f / 255.0f)
                           ? fmaxf(1.0f - al0, 0.01f) : 1.0f;
                om1[k] = (al1 >= 1.0f / 255.0f)
                           ? fmaxf(1.0f - al1, 0.01f) : 1.0f;
            }

            // ---- phase 2: prefix-product compositing (no serial chain) --
            float P0[8], P1[8];
            prefix8(om0, P0);
            prefix8(om1, P1);
            group8(P0, C, gb, Tg0, T0, r0, g0, b0, d0, cnt0, last0);
            group8(P1, C, gb, Tg1, T1, r1, g1, b1, d1, cnt1, last1);
        }
        // exact skip: Tg==0 makes all remaining steps no-ops
        if (__all((Tg0 == 0.0f) && (Tg1 == 0.0f))) break;
    }

    // ---- write outputs (image layout) ----
    const int c    = tu * TILE + pu;
    const int row0 = tv * TILE + pv0;
    const int pix0 = row0 * W + c;
    const int pix1 = pix0 + 8 * W;

    const float norm0 = 1.0f - T0;   // == sum(w) by telescoping
    const float norm1 = 1.0f - T1;

    out[pix0 * 3 + 0] = r0;
    out[pix0 * 3 + 1] = g0;
    out[pix0 * 3 + 2] = b0;
    out[n_pix * 3 + pix0] = d0 / fmaxf(norm0, 1e-6f);
    out[n_pix * 4 + pix0] = norm0;
    out[n_pix * 5 + pix0] = (float)(t * PPT + last0);
    out[n_pix * 6 + pix0] = (float)cnt0;

    out[pix1 * 3 + 0] = r1;
    out[pix1 * 3 + 1] = g1;
    out[pix1 * 3 + 2] = b1;
    out[n_pix * 3 + pix1] = d1 / fmaxf(norm1, 1e-6f);
    out[n_pix * 4 + pix1] = norm1;
    out[n_pix * 5 + pix1] = (float)(t * PPT + last1);
    out[n_pix * 6 + pix1] = (float)cnt1;
}

extern "C" void kernel_launch(void* const* d_in, const int* in_sizes, int n_in,
                              void* d_out, int out_size, void* d_ws, size_t ws_size,
                              hipStream_t stream) {
    const float* point_uv    = (const float*)d_in[0];
    const float* point_conic = (const float*)d_in[1];
    const float* point_alpha = (const float*)d_in[2];
    const float* point_color = (const float*)d_in[3];
    const float* point_depth = (const float*)d_in[4];
    const int*   tpi         = (const int*)d_in[5];
    const int*   cam_h       = (const int*)d_in[6];
    const int*   cam_w       = (const int*)d_in[7];

    const int NT = in_sizes[5] / PPT;  // number of tiles

    gsplat_raster_kernel<<<NT, 128, 0, stream>>>(
        point_uv, point_conic, point_alpha, point_color, point_depth,
        tpi, cam_h, cam_w, (float*)d_out);
}